// Round 1
// baseline (202.346 us; speedup 1.0000x reference)
//
#include <hip/hip_runtime.h>
#include <hip/hip_bf16.h>

// LCN spiking net, fully fused.
// Key facts exploited:
//  - Synaptic update with zero carried state is the identity: layer = gather-matvec + bias.
//  - Output only uses t = T-1  -> process 32 rows, not 640 (20x work cut).
//  - Rows independent end-to-end -> one block per row, LDS ping-pong, single launch.

#define ROWS 32
#define TSTEPS 20
#define D0 14400
#define D1 7200
#define D2 3600
#define D3 1800
#define D4 900
#define D5 450
#define KNB 25

__device__ __forceinline__ void lcn_layer(const float* __restrict__ hin,
                                          float* __restrict__ hout,
                                          const float* __restrict__ w,
                                          const float* __restrict__ bvec,
                                          const int* __restrict__ knn,
                                          int dout)
{
    for (int j = threadIdx.x; j < dout; j += blockDim.x) {
        const int*   kn = knn + j * KNB;
        const float* ww = w   + j * KNB;
        float acc = bvec[j];
#pragma unroll
        for (int k = 0; k < KNB; ++k) {
            acc += hin[kn[k]] * ww[k];
        }
        hout[j] = acc;
    }
}

__global__ __launch_bounds__(1024)
void lcn_fused(const float* __restrict__ x,
               const float* __restrict__ w0, const float* __restrict__ b0, const int* __restrict__ knn0,
               const float* __restrict__ w1, const float* __restrict__ b1, const int* __restrict__ knn1,
               const float* __restrict__ w2, const float* __restrict__ b2, const int* __restrict__ knn2,
               const float* __restrict__ w3, const float* __restrict__ b3, const int* __restrict__ knn3,
               const float* __restrict__ w4, const float* __restrict__ b4, const int* __restrict__ knn4,
               const float* __restrict__ Wfc, const float* __restrict__ bfc,
               float* __restrict__ out)
{
    __shared__ float bufA[D1];   // 7200 floats (28.8 KB)
    __shared__ float bufB[D2];   // 3600 floats (14.4 KB)

    const int row = blockIdx.x;  // 0..31
    // only the last timestep matters: row b uses x[b, T-1, :]
    const float* xrow = x + ((size_t)row * TSTEPS + (TSTEPS - 1)) * (size_t)D0;

    // layer 0: global gather -> bufA[0..7199]
    lcn_layer(xrow, bufA, w0, b0, knn0, D1);
    __syncthreads();

    // layer 1: bufA -> bufB[0..3599]
    lcn_layer(bufA, bufB, w1, b1, knn1, D2);
    __syncthreads();

    // layer 2: bufB -> bufA[0..1799]
    lcn_layer(bufB, bufA, w2, b2, knn2, D3);
    __syncthreads();

    // layer 3: bufA -> bufB[0..899]   (h2 in bufB is dead now)
    lcn_layer(bufA, bufB, w3, b3, knn3, D4);
    __syncthreads();

    // layer 4: bufB -> bufA[0..449]
    lcn_layer(bufB, bufA, w4, b4, knn4, D5);
    __syncthreads();

    // fc: out[row, o] = sum_i bufA[i] * Wfc[i*2+o] + bfc[o]
    const int lane = threadIdx.x & 63;
    const int wid  = threadIdx.x >> 6;
    if (wid < 2) {
        float p = 0.0f;
        for (int i = lane; i < D5; i += 64)
            p += bufA[i] * Wfc[i * 2 + wid];
#pragma unroll
        for (int off = 32; off; off >>= 1)
            p += __shfl_down(p, off, 64);
        if (lane == 0)
            out[row * 2 + wid] = p + bfc[wid];
    }
}

extern "C" void kernel_launch(void* const* d_in, const int* in_sizes, int n_in,
                              void* d_out, int out_size, void* d_ws, size_t ws_size,
                              hipStream_t stream)
{
    // setup_inputs() dict order:
    // 0:x, then per layer i: w{i}, b{i}, knn{i}  (i=0..4), then Wfc, bfc
    const float* x    = (const float*)d_in[0];
    const float* w0   = (const float*)d_in[1];
    const float* b0   = (const float*)d_in[2];
    const int*   knn0 = (const int*)  d_in[3];
    const float* w1   = (const float*)d_in[4];
    const float* b1   = (const float*)d_in[5];
    const int*   knn1 = (const int*)  d_in[6];
    const float* w2   = (const float*)d_in[7];
    const float* b2   = (const float*)d_in[8];
    const int*   knn2 = (const int*)  d_in[9];
    const float* w3   = (const float*)d_in[10];
    const float* b3   = (const float*)d_in[11];
    const int*   knn3 = (const int*)  d_in[12];
    const float* w4   = (const float*)d_in[13];
    const float* b4   = (const float*)d_in[14];
    const int*   knn4 = (const int*)  d_in[15];
    const float* Wfc  = (const float*)d_in[16];
    const float* bfc  = (const float*)d_in[17];
    float* out = (float*)d_out;

    lcn_fused<<<dim3(ROWS), dim3(1024), 0, stream>>>(
        x,
        w0, b0, knn0,
        w1, b1, knn1,
        w2, b2, knn2,
        w3, b3, knn3,
        w4, b4, knn4,
        Wfc, bfc,
        out);
}

// Round 2
// 146.397 us; speedup vs baseline: 1.3822x; 1.3822x over previous
//
#include <hip/hip_runtime.h>
#include <hip/hip_bf16.h>

// LCN spiking net, round 2: parallelism over fusion.
//  - Spiking update is identity -> each layer = sparse gather-matvec + bias.
//  - Only t = T-1 contributes -> 32 rows.
//  - Rounds 0/1 showed the 32-block fully-fused kernel is latency-bound
//    (VALUBusy 0.9%, occupancy 5.5%). Now: big layers get one thread per
//    (row, output) across the whole chip; only the tiny tail stays fused.

#define ROWS 32
#define TSTEPS 20
#define D0 14400
#define D1 7200
#define D2 3600
#define D3 1800
#define D4 900
#define D5 450
#define KNB 25

// Generic gather-matvec layer: one thread per (row, j).
__global__ __launch_bounds__(256)
void lcn_layer_k(const float* __restrict__ hin_base, long long row_stride,
                 float* __restrict__ hout, int dout,
                 const float* __restrict__ w, const float* __restrict__ bvec,
                 const int* __restrict__ knn)
{
    const int j = blockIdx.x * blockDim.x + threadIdx.x;
    const int row = blockIdx.y;
    if (j >= dout) return;
    const float* hin = hin_base + (long long)row * row_stride;
    const int*   kn  = knn + j * KNB;
    const float* ww  = w   + j * KNB;
    float acc = bvec[j];
#pragma unroll
    for (int k = 0; k < KNB; ++k)
        acc += hin[kn[k]] * ww[k];
    hout[row * dout + j] = acc;
}

// Fused tail: layer3 (1800->900), layer4 (900->450), fc (450->2).
// One block per row; LDS chains are short so latency is acceptable here.
__global__ __launch_bounds__(1024)
void lcn_tail(const float* __restrict__ h3,   // [ROWS][D3]
              const float* __restrict__ w3, const float* __restrict__ b3, const int* __restrict__ knn3,
              const float* __restrict__ w4, const float* __restrict__ b4, const int* __restrict__ knn4,
              const float* __restrict__ Wfc, const float* __restrict__ bfc,
              float* __restrict__ out)
{
    __shared__ float s3[D3];
    __shared__ float s4[D4];
    __shared__ float s5[D5];

    const int row = blockIdx.x;
    const float* hrow = h3 + row * D3;

    for (int i = threadIdx.x; i < D3; i += blockDim.x)
        s3[i] = hrow[i];
    __syncthreads();

    for (int j = threadIdx.x; j < D4; j += blockDim.x) {
        const int*   kn = knn3 + j * KNB;
        const float* ww = w3   + j * KNB;
        float acc = b3[j];
#pragma unroll
        for (int k = 0; k < KNB; ++k)
            acc += s3[kn[k]] * ww[k];
        s4[j] = acc;
    }
    __syncthreads();

    for (int j = threadIdx.x; j < D5; j += blockDim.x) {
        const int*   kn = knn4 + j * KNB;
        const float* ww = w4   + j * KNB;
        float acc = b4[j];
#pragma unroll
        for (int k = 0; k < KNB; ++k)
            acc += s4[kn[k]] * ww[k];
        s5[j] = acc;
    }
    __syncthreads();

    const int lane = threadIdx.x & 63;
    const int wid  = threadIdx.x >> 6;
    if (wid < 2) {
        float p = 0.0f;
        for (int i = lane; i < D5; i += 64)
            p += s5[i] * Wfc[i * 2 + wid];
#pragma unroll
        for (int off = 32; off; off >>= 1)
            p += __shfl_down(p, off, 64);
        if (lane == 0)
            out[row * 2 + wid] = p + bfc[wid];
    }
}

extern "C" void kernel_launch(void* const* d_in, const int* in_sizes, int n_in,
                              void* d_out, int out_size, void* d_ws, size_t ws_size,
                              hipStream_t stream)
{
    const float* x    = (const float*)d_in[0];
    const float* w0   = (const float*)d_in[1];
    const float* b0   = (const float*)d_in[2];
    const int*   knn0 = (const int*)  d_in[3];
    const float* w1   = (const float*)d_in[4];
    const float* b1   = (const float*)d_in[5];
    const int*   knn1 = (const int*)  d_in[6];
    const float* w2   = (const float*)d_in[7];
    const float* b2   = (const float*)d_in[8];
    const int*   knn2 = (const int*)  d_in[9];
    const float* w3   = (const float*)d_in[10];
    const float* b3   = (const float*)d_in[11];
    const int*   knn3 = (const int*)  d_in[12];
    const float* w4   = (const float*)d_in[13];
    const float* b4   = (const float*)d_in[14];
    const int*   knn4 = (const int*)  d_in[15];
    const float* Wfc  = (const float*)d_in[16];
    const float* bfc  = (const float*)d_in[17];
    float* out = (float*)d_out;

    // workspace layout (floats): h1[32][7200] | h2[32][3600] | h3[32][1800]
    float* h1 = (float*)d_ws;            // 230400 floats
    float* h2 = h1 + ROWS * D1;          // 115200 floats
    float* h3 = h2 + ROWS * D2;          //  57600 floats  (total 1.6 MB)

    // layer 0: x[:, T-1, :] (row stride T*D0) -> h1
    lcn_layer_k<<<dim3((D1 + 255) / 256, ROWS), dim3(256), 0, stream>>>(
        x + (size_t)(TSTEPS - 1) * D0, (long long)TSTEPS * D0, h1, D1, w0, b0, knn0);

    // layer 1: h1 -> h2
    lcn_layer_k<<<dim3((D2 + 255) / 256, ROWS), dim3(256), 0, stream>>>(
        h1, D1, h2, D2, w1, b1, knn1);

    // layer 2: h2 -> h3
    lcn_layer_k<<<dim3((D3 + 255) / 256, ROWS), dim3(256), 0, stream>>>(
        h2, D2, h3, D3, w2, b2, knn2);

    // layers 3+4+fc fused, one block per row
    lcn_tail<<<dim3(ROWS), dim3(1024), 0, stream>>>(
        h3, w3, b3, knn3, w4, b4, knn4, Wfc, bfc, out);
}

// Round 3
// 132.194 us; speedup vs baseline: 1.5307x; 1.1074x over previous
//
#include <hip/hip_runtime.h>
#include <hip/hip_bf16.h>

// LCN spiking net, round 3.
//  - Spiking update is identity; only t=T-1 matters -> 32 rows.
//  - Harness reset (268 MB ws poison ~43us + input restore ~13us) is a fixed
//    floor inside the timed window; optimize only the ~80us of kernel time.
//  - Gathers from global rows split into ~60 L1 lines per wave; stage the
//    input row in LDS instead (random ds_read ~10cyc/wave) and split each
//    row across multiple blocks for occupancy.

#define ROWS 32
#define TSTEPS 20
#define D0 14400
#define D1 7200
#define D2 3600
#define D3 1800
#define D4 900
#define D5 450
#define KNB 25

// Generic LDS-staged gather layer. Grid: (DOUT/JPB, ROWS), block 256.
template <int DIN, int DOUT, int JPB>
__global__ __launch_bounds__(256)
void layer_lds(const float* __restrict__ hin_base, long long row_stride,
               float* __restrict__ hout,
               const float* __restrict__ w, const float* __restrict__ bvec,
               const int* __restrict__ knn)
{
    __shared__ float s[DIN];
    const int row = blockIdx.y;
    const float* hin = hin_base + (long long)row * row_stride;

    // coalesced float4 stage of the whole input row
    const float4* src = reinterpret_cast<const float4*>(hin);
    float4* dst = reinterpret_cast<float4*>(s);
#pragma unroll 1
    for (int i = threadIdx.x; i < DIN / 4; i += 256)
        dst[i] = src[i];
    __syncthreads();

    const int j0 = blockIdx.x * JPB;
#pragma unroll 1
    for (int j = j0 + threadIdx.x; j < j0 + JPB; j += 256) {
        const int*   kn = knn + j * KNB;
        const float* ww = w   + j * KNB;
        float acc = bvec[j];
#pragma unroll
        for (int k = 0; k < KNB; ++k)
            acc += s[kn[k]] * ww[k];
        hout[row * DOUT + j] = acc;
    }
}

// Layer 4 (900->450) + FC (450->2), one block per row.
__global__ __launch_bounds__(256)
void lcn_l4_fc(const float* __restrict__ h4,   // [ROWS][D4]
               const float* __restrict__ w4, const float* __restrict__ b4, const int* __restrict__ knn4,
               const float* __restrict__ Wfc, const float* __restrict__ bfc,
               float* __restrict__ out)
{
    __shared__ float s4[D4];
    __shared__ float s5[D5];

    const int row = blockIdx.x;
    const float* hrow = h4 + row * D4;
    for (int i = threadIdx.x; i < D4; i += 256)
        s4[i] = hrow[i];
    __syncthreads();

    for (int j = threadIdx.x; j < D5; j += 256) {
        const int*   kn = knn4 + j * KNB;
        const float* ww = w4   + j * KNB;
        float acc = b4[j];
#pragma unroll
        for (int k = 0; k < KNB; ++k)
            acc += s4[kn[k]] * ww[k];
        s5[j] = acc;
    }
    __syncthreads();

    const int lane = threadIdx.x & 63;
    const int wid  = threadIdx.x >> 6;
    if (wid < 2) {
        float p = 0.0f;
        for (int i = lane; i < D5; i += 64)
            p += s5[i] * Wfc[i * 2 + wid];
#pragma unroll
        for (int off = 32; off; off >>= 1)
            p += __shfl_down(p, off, 64);
        if (lane == 0)
            out[row * 2 + wid] = p + bfc[wid];
    }
}

extern "C" void kernel_launch(void* const* d_in, const int* in_sizes, int n_in,
                              void* d_out, int out_size, void* d_ws, size_t ws_size,
                              hipStream_t stream)
{
    const float* x    = (const float*)d_in[0];
    const float* w0   = (const float*)d_in[1];
    const float* b0   = (const float*)d_in[2];
    const int*   knn0 = (const int*)  d_in[3];
    const float* w1   = (const float*)d_in[4];
    const float* b1   = (const float*)d_in[5];
    const int*   knn1 = (const int*)  d_in[6];
    const float* w2   = (const float*)d_in[7];
    const float* b2   = (const float*)d_in[8];
    const int*   knn2 = (const int*)  d_in[9];
    const float* w3   = (const float*)d_in[10];
    const float* b3   = (const float*)d_in[11];
    const int*   knn3 = (const int*)  d_in[12];
    const float* w4   = (const float*)d_in[13];
    const float* b4   = (const float*)d_in[14];
    const int*   knn4 = (const int*)  d_in[15];
    const float* Wfc  = (const float*)d_in[16];
    const float* bfc  = (const float*)d_in[17];
    float* out = (float*)d_out;

    // workspace (floats): h1[32][7200] | h2[32][3600] | h3[32][1800] | h4[32][900]
    float* h1 = (float*)d_ws;
    float* h2 = h1 + ROWS * D1;
    float* h3 = h2 + ROWS * D2;
    float* h4 = h3 + ROWS * D3;

    // layer 0: x[:, T-1, :] -> h1   (8 blocks/row, 57.6 KB LDS each)
    layer_lds<D0, D1, 900><<<dim3(D1 / 900, ROWS), dim3(256), 0, stream>>>(
        x + (size_t)(TSTEPS - 1) * D0, (long long)TSTEPS * D0, h1, w0, b0, knn0);

    // layer 1: h1 -> h2   (8 blocks/row)
    layer_lds<D1, D2, 450><<<dim3(D2 / 450, ROWS), dim3(256), 0, stream>>>(
        h1, D1, h2, w1, b1, knn1);

    // layer 2: h2 -> h3   (4 blocks/row)
    layer_lds<D2, D3, 450><<<dim3(D3 / 450, ROWS), dim3(256), 0, stream>>>(
        h2, D2, h3, w2, b2, knn2);

    // layer 3: h3 -> h4   (4 blocks/row)
    layer_lds<D3, D4, 225><<<dim3(D4 / 225, ROWS), dim3(256), 0, stream>>>(
        h3, D3, h4, w3, b3, knn3);

    // layer 4 + fc, one block per row
    lcn_l4_fc<<<dim3(ROWS), dim3(256), 0, stream>>>(
        h4, w4, b4, knn4, Wfc, bfc, out);
}